// Round 1
// baseline (136.268 us; speedup 1.0000x reference)
//
#include <hip/hip_runtime.h>

// Problem constants (match reference setup_inputs / globals)
#define KTAPS   10     // K
#define SKIP    2
#define TRANS   100    // TRANSIENTS
#define NMONO   220    // C(10+3-1, 3)
#define NFEAT   231    // 1 + K + NMONO
#define NIN     4096   // time length of X
#define NT      (NIN - TRANS)   // 3996 output time steps
#define NROWS   32     // 8 * 4
#define TTILE   128    // time steps per block
#define PAD     ((KTAPS - 1) * SKIP)  // 18

// Monomial table: for monomial m = (i<=j<=l) store (2i) | (2j<<8) | (2l<<16),
// pre-doubled because the LDS tap offset is 2*k. Lex order matches
// itertools.combinations_with_replacement(range(10), 3).
struct MonomTable {
    int v[NMONO];
    constexpr MonomTable() : v{} {
        int m = 0;
        for (int i = 0; i < KTAPS; ++i)
            for (int j = i; j < KTAPS; ++j)
                for (int l = j; l < KTAPS; ++l)
                    v[m++] = (2 * i) | ((2 * j) << 8) | ((2 * l) << 16);
    }
};
__constant__ MonomTable g_mt = MonomTable();

__global__ __launch_bounds__(256) void nvar_kernel(const float* __restrict__ X,
                                                   float* __restrict__ out) {
    const int tile = blockIdx.x;           // time tile
    const int row  = blockIdx.y;           // b*4 + r
    const int t0   = tile * TTILE;
    const int tcount = min(TTILE, NT - t0);      // 128 or 28 (both %4 == 0)

    // Stage X window: output step (t0+tl) needs X[t0 + 82 + tl + 2k], k=0..9
    __shared__ float xs[TTILE + PAD];
    const float* xrow = X + (size_t)row * NIN;
    const int base_in = t0 + TRANS - PAD;        // >= 82, always in-bounds
    const int wlen = tcount + PAD;
    for (int i = threadIdx.x; i < wlen; i += blockDim.x)
        xs[i] = xrow[base_in + i];
    __syncthreads();

    // Flat output for this tile: tcount * NFEAT floats, 16B-aligned base.
    float* orow = out + ((size_t)row * NT + t0) * NFEAT;
    const int total4 = (tcount * NFEAT) >> 2;    // exact (no remainder)

    for (int e4 = threadIdx.x; e4 < total4; e4 += blockDim.x) {
        const int e0 = e4 << 2;
        int tl = (unsigned)e0 / NFEAT;           // magic-mul division
        int f  = e0 - tl * NFEAT;
        float vals[4];
#pragma unroll
        for (int u = 0; u < 4; ++u) {
            float v;
            if (f == 0) {
                v = 1.0f;
            } else if (f <= KTAPS) {
                v = xs[tl + 2 * (f - 1)];
            } else {
                const int m = g_mt.v[f - (KTAPS + 1)];
                const float a = xs[tl + (m & 0xff)];
                const float b = xs[tl + ((m >> 8) & 0xff)];
                const float c = xs[tl + (m >> 16)];
                v = a * b * c;
            }
            vals[u] = v;
            if (++f == NFEAT) { f = 0; ++tl; }
        }
        reinterpret_cast<float4*>(orow)[e4] =
            make_float4(vals[0], vals[1], vals[2], vals[3]);
    }
}

extern "C" void kernel_launch(void* const* d_in, const int* in_sizes, int n_in,
                              void* d_out, int out_size, void* d_ws, size_t ws_size,
                              hipStream_t stream) {
    const float* X = (const float*)d_in[0];
    float* out = (float*)d_out;
    dim3 grid((NT + TTILE - 1) / TTILE, NROWS);  // 32 x 32 = 1024 blocks
    nvar_kernel<<<grid, 256, 0, stream>>>(X, out);
}

// Round 2
// 124.972 us; speedup vs baseline: 1.0904x; 1.0904x over previous
//
#include <hip/hip_runtime.h>

#define KTAPS 10
#define SKIP  2
#define TRANS 100
#define PAD   ((KTAPS - 1) * SKIP)   // 18
#define NMONO 220
#define NFEAT 231                    // 1 + 10 + 220
#define NIN   4096
#define NT    (NIN - TRANS)          // 3996
#define NROWS 32                     // 8*4
#define TT    64                     // timesteps per block
#define RS    233                    // LDS row stride in words; 233%32=9 (odd) -> conflict-free writes

__global__ __launch_bounds__(256) void nvar_kernel(const float* __restrict__ X,
                                                   float* __restrict__ out) {
    __shared__ float feat[TT * RS];          // 59,648 B -> 2 blocks/CU

    const int tile = blockIdx.x;
    const int row  = blockIdx.y;
    const int t0   = tile * TT;
    const int tcount = min(TT, NT - t0);     // 64 or 28

    const int tl = threadIdx.x & 63;         // lane = local timestep
    const int wq = __builtin_amdgcn_readfirstlane(threadIdx.x >> 6);  // wave id, uniform

    // clamp duplicate (tail) timesteps; their LDS rows are never copied out
    int tg = t0 + tl;
    if (tg >= NT) tg = NT - 1;

    // Load the 10 taps for this timestep directly from global (coalesced, L2-hot):
    // lin_k(t) = X[row, t + TRANS - PAD + 2k], max index 3995+82+18 = 4095, in-bounds.
    const float* xrow = X + (size_t)row * NIN;
    float tap[KTAPS];
#pragma unroll
    for (int k = 0; k < KTAPS; ++k)
        tap[k] = xrow[tg + (TRANS - PAD) + 2 * k];

    float* frow = feat + tl * RS;

    // Wave 0 writes the ones-column and linear features.
    if (wq == 0) {
        frow[0] = 1.0f;
#pragma unroll
        for (int k = 0; k < KTAPS; ++k)
            frow[1 + k] = tap[k];
    }

    // Pair-index quarters (balanced monomial counts 45/55/61/59; wq0 also has 11 lin):
    const int plo = (wq == 0) ? 0 : (wq == 1) ? 6 : (wq == 2) ? 19 : 32;
    const int phi = (wq == 0) ? 6 : (wq == 1) ? 19 : (wq == 2) ? 32 : 55;

    // Fully unrolled i<=j<=l monomial enumeration; p and fbase become constants,
    // the (p>=plo && p<phi) guard is a wave-uniform scalar branch.
    {
        int p = 0, fbase = 1 + KTAPS;
#pragma unroll
        for (int i = 0; i < KTAPS; ++i) {
#pragma unroll
            for (int j = i; j < KTAPS; ++j) {
                if (p >= plo && p < phi) {
                    const float pij = tap[i] * tap[j];
#pragma unroll
                    for (int l = j; l < KTAPS; ++l)
                        frow[fbase + (l - j)] = pij * tap[l];
                }
                fbase += KTAPS - j;
                ++p;
            }
        }
    }

    __syncthreads();

    // Cooperative flat copy LDS -> global, float2 (8B/lane) stores.
    // tcount*NFEAT is even (64*231=14784, 28*231=6468).
    const int total2 = (tcount * NFEAT) >> 1;
    float* obase = out + ((size_t)row * NT + t0) * NFEAT;   // 16B-aligned (231*4 | base)
    for (int e2 = threadIdx.x; e2 < total2; e2 += 256) {
        const int e0 = e2 << 1;
        const int t  = (unsigned)e0 / NFEAT;     // magic-mul div
        const int f  = e0 - t * NFEAT;
        const int base = t * RS + f;
        const float a0 = feat[base];
        // second element may wrap into the next row (skip the 2-word pad)
        const float a1 = feat[base + 1 + ((f + 1 >= NFEAT) ? (RS - NFEAT) : 0)];
        reinterpret_cast<float2*>(obase)[e2] = make_float2(a0, a1);
    }
}

extern "C" void kernel_launch(void* const* d_in, const int* in_sizes, int n_in,
                              void* d_out, int out_size, void* d_ws, size_t ws_size,
                              hipStream_t stream) {
    const float* X = (const float*)d_in[0];
    float* out = (float*)d_out;
    dim3 grid((NT + TT - 1) / TT, NROWS);    // 63 x 32 = 2016 blocks
    nvar_kernel<<<grid, 256, 0, stream>>>(X, out);
}

// Round 3
// 121.343 us; speedup vs baseline: 1.1230x; 1.0299x over previous
//
#include <hip/hip_runtime.h>

#define KTAPS 10
#define SKIP  2
#define TRANS 100
#define PAD   ((KTAPS - 1) * SKIP)   // 18
#define NFEAT 231                    // 1 + 10 + 220
#define NIN   4096
#define NT    (NIN - TRANS)          // 3996
#define NROWS 32                     // 8*4
#define TT    32                     // timesteps per block

// Emit monomials for pair-index range [PLO,PHI) of the i<=j pairs (55 total),
// fully unrolled so every f-offset and tap index is a compile-time constant.
// Lex order matches itertools.combinations_with_replacement(range(10), 3).
template<int PLO, int PHI, bool LIN>
__device__ __forceinline__ void emit_features(const float* __restrict__ tap,
                                              float* __restrict__ frow) {
    if (LIN) {
        frow[0] = 1.0f;
#pragma unroll
        for (int k = 0; k < KTAPS; ++k) frow[1 + k] = tap[k];
    }
    int p = 0, fb = 1 + KTAPS;
#pragma unroll
    for (int i = 0; i < KTAPS; ++i) {
#pragma unroll
        for (int j = i; j < KTAPS; ++j) {
            if (p >= PLO && p < PHI) {           // folds: PLO/PHI/p all constants
                const float pij = tap[i] * tap[j];
#pragma unroll
                for (int l = j; l < KTAPS; ++l)
                    frow[fb + (l - j)] = pij * tap[l];
            }
            fb += KTAPS - j;
            ++p;
        }
    }
}

__global__ __launch_bounds__(256, 5) void nvar_kernel(const float* __restrict__ X,
                                                      float* __restrict__ out) {
    // LDS tile laid out EXACTLY like the output slab: [t][feat], stride 231.
    // 231 % 32 = 7 (odd) -> compute-phase writes (fixed f, t=lane) hit 32
    // distinct banks. 32*231*4 = 29,568 B -> 5 blocks/CU.
    __shared__ float feat[TT * NFEAT];

    const int tile = blockIdx.x;
    const int row  = blockIdx.y;
    const int t0   = tile * TT;
    const int tcount = min(TT, NT - t0);         // 32 or 28 (tail)

    const int tl = threadIdx.x & 31;             // local timestep (both wave halves)
    const int wq = threadIdx.x >> 6;             // wave id, wave-uniform

    int tg = t0 + tl;
    if (tg >= NT) tg = NT - 1;                   // tail clamp; extra rows unused

    // lin_k(t) = X[row, t + 82 + 2k]; max index 3995+82+18 = 4095, in-bounds.
    const float* xrow = X + (size_t)row * NIN;
    float tap[KTAPS];
#pragma unroll
    for (int k = 0; k < KTAPS; ++k)
        tap[k] = xrow[tg + (TRANS - PAD) + 2 * k];

    // Upper and lower 32 lanes of each wave duplicate the same rows (identical
    // values -> benign same-address LDS writes, no divergence).
    float* frow = feat + tl * NFEAT;
    switch (wq) {                                // balanced writes: 56/55/58/62
        case 0:  emit_features< 0,  6, true >(tap, frow); break;
        case 1:  emit_features< 6, 19, false>(tap, frow); break;
        case 2:  emit_features<19, 31, false>(tap, frow); break;
        default: emit_features<31, 55, false>(tap, frow); break;
    }

    __syncthreads();

    // Flat float4 copy: LDS layout == output layout. tcount*NFEAT % 4 == 0,
    // and the global base offset is a multiple of 4 floats -> 16B-aligned.
    const int total4 = (tcount * NFEAT) >> 2;    // 1848 or 1617
    float4* __restrict__ o4 =
        reinterpret_cast<float4*>(out + ((size_t)row * NT + t0) * NFEAT);
    const float4* s4 = reinterpret_cast<const float4*>(feat);
    for (int i = threadIdx.x; i < total4; i += 256)
        o4[i] = s4[i];
}

extern "C" void kernel_launch(void* const* d_in, const int* in_sizes, int n_in,
                              void* d_out, int out_size, void* d_ws, size_t ws_size,
                              hipStream_t stream) {
    const float* X = (const float*)d_in[0];
    float* out = (float*)d_out;
    dim3 grid((NT + TT - 1) / TT, NROWS);        // 125 x 32 = 4000 blocks
    nvar_kernel<<<grid, 256, 0, stream>>>(X, out);
}